// Round 2
// baseline (2234.989 us; speedup 1.0000x reference)
//
#include <hip/hip_runtime.h>

// ============================================================================
// CNF log-density, fused persistent kernel — v3: barrier-free waves.
//   - ZERO __syncthreads. Weights are read per-wave straight from global
//     (L2-resident, fragment-linear layout) into registers: one coalesced
//     global_load_dwordx4 per B-fragment. No shared weight staging -> no
//     block-wide lockstep; each wave runs at its own pace and 2 waves/SIMD
//     (2 blocks/CU) overlap each other's load latency.
//   - Wave owns 16 rows x full N. Transpose buffer and RK k-slabs are
//     wave-private (same-wave DS ops are ordered; no barriers needed).
//   - Register diet for a clean <=256-reg fit at 2 waves/SIMD:
//       * k-slabs stored bf16 in LDS (k's feed a bf16 MFMA pack anyway)
//       * tangent A-frags re-read per kt from LDS (t stays in tb)
//       * eps fp32 copy dropped; div dot reconstructs from bf16 e0/e1
// ============================================================================

#define DIM   64
#define HID   256
#define BATCH 32768
#define LOG2PI_HALF_SUM 58.8120661251f   // 32 * log(2*pi)

typedef float  floatx4 __attribute__((ext_vector_type(4)));
typedef short  short8  __attribute__((ext_vector_type(8)));

// ---- workspace layout (bytes), fragment-linear bf16 weights ----
#define W1OFF 0          // 2 kt * 16 nt * 1KB  = 32768
#define W2OFF 32768      // 8 kt * 16 nt * 1KB  = 131072
#define W3OFF 163840     // 131072
#define W4OFF 294912     // 8 kt * 4 nt * 1KB   = 32768
#define BOFF  327680     // biases fp32: b1[256] b2[256] b3[256] b4[64]

// ---- per-wave LDS region (bytes) ----
#define TBSTRIDE 264                 // shorts per transpose-buffer row (256+8)
#define SLABOFF  8448                // 16 * 264 * 2
#define SLABSTR  72                  // shorts per slab row (64 + 8 pad)
#define SLABSH   1152                // shorts per slab: 16 * 72
#define WAVELDS  19968               // 8448 + 5 * 2304
#define SMEM_BYTES (4 * WAVELDS)     // 79872 -> 2 blocks/CU (159.7KB/160KB)

__device__ __forceinline__ short f2bf(float f) {
    union { float f; unsigned u; } v; v.f = f;
    unsigned r = v.u + 0x7FFFu + ((v.u >> 16) & 1u);   // RTNE
    return (short)(r >> 16);
}

__device__ __forceinline__ float bf2f(short s) {
    union { float f; unsigned u; } v;
    v.u = ((unsigned)(unsigned short)s) << 16;
    return v.f;
}

__device__ __forceinline__ float fast_tanh(float x) {
    float e = __expf(2.0f * x);
    return 1.0f - 2.0f * __builtin_amdgcn_rcpf(e + 1.0f);
}

// Wave-private activation transpose: tanh in place, write bf16 h to tb, read
// back value A-frags; write tangent t over tb (read back per-kt by caller).
// Same-wave DS ordering makes this barrier-free.
__device__ __forceinline__ void act_transpose(floatx4* av, floatx4* at,
                                              short8* Av, short* tbs,
                                              int m, int kq) {
#pragma unroll
    for (int nt = 0; nt < 16; nt++)
#pragma unroll
        for (int i = 0; i < 4; i++) {
            float hv = fast_tanh(av[nt][i]);
            av[nt][i] = hv;                      // keep h for tangent scaling
            tbs[(kq * 4 + i) * TBSTRIDE + nt * 16 + m] = f2bf(hv);
        }
#pragma unroll
    for (int kt = 0; kt < 8; kt++)
        Av[kt] = *(const short8*)&tbs[m * TBSTRIDE + kt * 32 + kq * 8];
#pragma unroll
    for (int nt = 0; nt < 16; nt++)
#pragma unroll
        for (int i = 0; i < 4; i++) {
            float tv = (1.0f - av[nt][i] * av[nt][i]) * at[nt][i];
            tbs[(kq * 4 + i) * TBSTRIDE + nt * 16 + m] = f2bf(tv);
        }
}

// One ODE f-eval, fully wave-local. dz written bf16 into slab[slab_out];
// returns div = sum_k Jeps*eps for row (lane&15), replicated across quads.
__device__ __forceinline__ float feval(short8 z0, short8 z1, short8 e0, short8 e1,
                                       const char* __restrict__ ws, char* wl,
                                       int slab_out, int lane, int m, int kq) {
    short* tbs = (short*)wl;
    float* tbf = (float*)wl;
    short* slab = (short*)(wl + SLABOFF) + slab_out * SLABSH;
    const float* bias = (const float*)(ws + BOFF);
    const int fo = lane * 16;                    // byte offset within fragment

    floatx4 av[16], at[16];
    short8  Av[8];
    const floatx4 zero4 = {0.f, 0.f, 0.f, 0.f};

    // ---------------- layer 1: K=64 (2 kt), N=256 ----------------
#pragma unroll
    for (int nt = 0; nt < 16; nt++) {
        float b = bias[nt * 16 + m];
        floatx4 bv = {b, b, b, b};
        av[nt] = bv; at[nt] = zero4;
    }
#pragma unroll
    for (int kt = 0; kt < 2; kt++) {
        short8 aV = kt ? z1 : z0;
        short8 aT = kt ? e1 : e0;
#pragma unroll
        for (int nt = 0; nt < 16; nt++) {
            short8 b = *(const short8*)(ws + W1OFF + (kt * 16 + nt) * 1024 + fo);
            av[nt] = __builtin_amdgcn_mfma_f32_16x16x32_bf16(aV, b, av[nt], 0, 0, 0);
            at[nt] = __builtin_amdgcn_mfma_f32_16x16x32_bf16(aT, b, at[nt], 0, 0, 0);
        }
    }
    act_transpose(av, at, Av, tbs, m, kq);

    // ---------------- layers 2,3: K=256 (8 kt), N=256 ----------------
#pragma unroll 1
    for (int layer = 0; layer < 2; layer++) {
        const char* wb = ws + (layer ? W3OFF : W2OFF);
        const float* bb = bias + 256 + layer * 256;
#pragma unroll
        for (int nt = 0; nt < 16; nt++) {
            float b = bb[nt * 16 + m];
            floatx4 bv = {b, b, b, b};
            av[nt] = bv; at[nt] = zero4;
        }
#pragma unroll
        for (int kt = 0; kt < 8; kt++) {
            short8 At = *(const short8*)&tbs[m * TBSTRIDE + kt * 32 + kq * 8];
#pragma unroll
            for (int nt = 0; nt < 16; nt++) {
                short8 b = *(const short8*)(wb + (kt * 16 + nt) * 1024 + fo);
                av[nt] = __builtin_amdgcn_mfma_f32_16x16x32_bf16(Av[kt], b, av[nt], 0, 0, 0);
                at[nt] = __builtin_amdgcn_mfma_f32_16x16x32_bf16(At,     b, at[nt], 0, 0, 0);
            }
        }
        act_transpose(av, at, Av, tbs, m, kq);
    }

    // ---------------- layer 4: K=256 (8 kt), N=64 ----------------
    floatx4 a4v[4], a4t[4];
#pragma unroll
    for (int nt = 0; nt < 4; nt++) {
        float b = bias[768 + nt * 16 + m];
        floatx4 bv = {b, b, b, b};
        a4v[nt] = bv; a4t[nt] = zero4;
    }
#pragma unroll
    for (int kt = 0; kt < 8; kt++) {
        short8 At = *(const short8*)&tbs[m * TBSTRIDE + kt * 32 + kq * 8];
#pragma unroll
        for (int nt = 0; nt < 4; nt++) {
            short8 b = *(const short8*)(ws + W4OFF + (kt * 4 + nt) * 1024 + fo);
            a4v[nt] = __builtin_amdgcn_mfma_f32_16x16x32_bf16(Av[kt], b, a4v[nt], 0, 0, 0);
            a4t[nt] = __builtin_amdgcn_mfma_f32_16x16x32_bf16(At,     b, a4t[nt], 0, 0, 0);
        }
    }

    // Epilogue: Jeps fp32 -> tb (transpose), dz bf16 -> k-slab. Wave-local.
#pragma unroll
    for (int nt = 0; nt < 4; nt++)
#pragma unroll
        for (int i = 0; i < 4; i++) {
            tbf[(kq * 4 + i) * 68 + nt * 16 + m] = a4t[nt][i];
            slab[(kq * 4 + i) * SLABSTR + nt * 16 + m] = f2bf(a4v[nt][i]);
        }
    float div = 0.f;
#pragma unroll
    for (int kt2 = 0; kt2 < 2; kt2++) {
        short8 ev = kt2 ? e1 : e0;
#pragma unroll
        for (int jj = 0; jj < 8; jj += 4) {
            floatx4 jv = *(const floatx4*)&tbf[m * 68 + kt2 * 32 + kq * 8 + jj];
#pragma unroll
            for (int j = 0; j < 4; j++) div += jv[j] * bf2f(ev[jj + j]);
        }
    }
    div += __shfl_xor(div, 16, 64);
    div += __shfl_xor(div, 32, 64);
    return div;
}

// zs = y + sum_s cf[s]*k_s (bf16 k-slabs), packed to bf16 A-fragments.
template <int NK>
__device__ __forceinline__ void combine_pack(const float* y, const float (&cf)[NK],
                                             const short* slabs, int m, int kq,
                                             short8& lo, short8& hi) {
#pragma unroll
    for (int kt = 0; kt < 2; kt++) {
        float a[8];
#pragma unroll
        for (int j = 0; j < 8; j++) a[j] = y[kt * 8 + j];
#pragma unroll
        for (int s = 0; s < NK; s++) {
            short8 kv = *(const short8*)&slabs[s * SLABSH + m * SLABSTR + kt * 32 + kq * 8];
#pragma unroll
            for (int j = 0; j < 8; j++) a[j] += cf[s] * bf2f(kv[j]);
        }
#pragma unroll
        for (int j = 0; j < 8; j++) {
            if (kt == 0) lo[j] = f2bf(a[j]);
            else         hi[j] = f2bf(a[j]);
        }
    }
}

__global__ void __launch_bounds__(256, 2)
cnf_main(const float* __restrict__ x, const float* __restrict__ eps,
         const char* __restrict__ ws, float* __restrict__ out) {
    extern __shared__ char smem[];
    const int tid  = threadIdx.x;
    const int lane = tid & 63;
    const int wave = tid >> 6;
    const int m  = lane & 15, kq = lane >> 4;
    char*  wl    = smem + wave * WAVELDS;
    short* slabs = (short*)(wl + SLABOFF);
    const int row = blockIdx.x * 64 + wave * 16 + m;

    float y[16];
    short8 e0, e1;
#pragma unroll
    for (int kt = 0; kt < 2; kt++)
#pragma unroll
        for (int q = 0; q < 2; q++) {
            floatx4 vx = *(const floatx4*)(x   + row * DIM + kt * 32 + kq * 8 + q * 4);
            floatx4 ve = *(const floatx4*)(eps + row * DIM + kt * 32 + kq * 8 + q * 4);
#pragma unroll
            for (int j = 0; j < 4; j++) {
                y[kt * 8 + q * 4 + j] = vx[j];
                short b = f2bf(ve[j]);
                if (kt == 0) e0[q * 4 + j] = b; else e1[q * 4 + j] = b;
            }
        }

    float ylogp = 0.f;
    short8 z0, z1;

#pragma unroll 1
    for (int step = 0; step < 4; step++) {
#pragma unroll
        for (int j = 0; j < 8; j++) { z0[j] = f2bf(y[j]); z1[j] = f2bf(y[8 + j]); }
        const float d1 = feval(z0, z1, e0, e1, ws, wl, 0, lane, m, kq);

        combine_pack<1>(y, {0.05f}, slabs, m, kq, z0, z1);
        const float d2 = feval(z0, z1, e0, e1, ws, wl, 1, lane, m, kq);
        (void)d2;                                           // b2 = 0

        combine_pack<2>(y, {0.01875f, 0.05625f}, slabs, m, kq, z0, z1);
        const float d3 = feval(z0, z1, e0, e1, ws, wl, 2, lane, m, kq);

        combine_pack<3>(y, {0.244444444f, -0.933333333f, 0.888888889f},
                        slabs, m, kq, z0, z1);
        const float d4 = feval(z0, z1, e0, e1, ws, wl, 3, lane, m, kq);

        combine_pack<4>(y, {0.738149672f, -2.898948331f, 2.455723213f,
                            -0.072702332f}, slabs, m, kq, z0, z1);
        const float d5 = feval(z0, z1, e0, e1, ws, wl, 4, lane, m, kq);

        combine_pack<5>(y, {0.711568813f, -2.689393939f, 2.226605679f,
                            0.069602273f, -0.068382826f}, slabs, m, kq, z0, z1);
        const float d6 = feval(z0, z1, e0, e1, ws, wl, 1, lane, m, kq);  // k6 -> k2 slab

        // y += sum(c_i k_i);  slabs: k1=0, k3=2, k4=3, k5=4, k6=1
#pragma unroll
        for (int kt = 0; kt < 2; kt++) {
            const int o = m * SLABSTR + kt * 32 + kq * 8;
            short8 k1v = *(const short8*)&slabs[0 * SLABSH + o];
            short8 k6v = *(const short8*)&slabs[1 * SLABSH + o];
            short8 k3v = *(const short8*)&slabs[2 * SLABSH + o];
            short8 k4v = *(const short8*)&slabs[3 * SLABSH + o];
            short8 k5v = *(const short8*)&slabs[4 * SLABSH + o];
#pragma unroll
            for (int j = 0; j < 8; j++)
                y[kt * 8 + j] += 0.022786458f * bf2f(k1v[j]) + 0.112309075f * bf2f(k3v[j])
                               + 0.162760417f * bf2f(k4v[j]) - 0.080593989f * bf2f(k5v[j])
                               + 0.032738095f * bf2f(k6v[j]);
        }
        ylogp -= 0.022786458f * d1 + 0.112309075f * d3 + 0.162760417f * d4
               - 0.080593989f * d5 + 0.032738095f * d6;
    }

    float nrm = 0.f;
#pragma unroll
    for (int i = 0; i < 16; i++) nrm += y[i] * y[i];
    nrm += __shfl_xor(nrm, 16, 64);
    nrm += __shfl_xor(nrm, 32, 64);
    float res = -0.5f * nrm - LOG2PI_HALF_SUM - ylogp;
    if (lane < 16) out[blockIdx.x * 64 + wave * 16 + lane] = res;
}

// ---- weight pre-shuffle: fp32 [N][K] -> bf16 fragment-linear ----
// frag = ktile*NT + ntile; lane l holds W[ntile*16+(l&15)][ktile*32+(l>>4)*8 + 0..7]
__global__ void prep_w(const float* __restrict__ W, short* __restrict__ outp,
                       int K, int NT, int KT) {
    int slot  = blockIdx.x * 256 + threadIdx.x;
    int total = KT * NT * 64;
    if (slot >= total) return;
    int lane  = slot & 63, frag = slot >> 6;
    int ntile = frag % NT, ktile = frag / NT;
    int n = ntile * 16 + (lane & 15);
    int k = ktile * 32 + (lane >> 4) * 8;
    short8 v;
#pragma unroll
    for (int j = 0; j < 8; j++) v[j] = f2bf(W[n * K + k + j]);
    *(short8*)(outp + slot * 8) = v;
}

__global__ void prep_b(const float* __restrict__ b1, const float* __restrict__ b2,
                       const float* __restrict__ b3, const float* __restrict__ b4,
                       float* __restrict__ dst) {
    int i = blockIdx.x * 256 + threadIdx.x;
    if (i < 256)      dst[i] = b1[i];
    else if (i < 512) dst[i] = b2[i - 256];
    else if (i < 768) dst[i] = b3[i - 512];
    else if (i < 832) dst[i] = b4[i - 768];
}

extern "C" void kernel_launch(void* const* d_in, const int* in_sizes, int n_in,
                              void* d_out, int out_size, void* d_ws, size_t ws_size,
                              hipStream_t stream) {
    const float* x   = (const float*)d_in[0];
    const float* eps = (const float*)d_in[1];
    const float* W1  = (const float*)d_in[2];
    const float* b1  = (const float*)d_in[3];
    const float* W2  = (const float*)d_in[4];
    const float* b2  = (const float*)d_in[5];
    const float* W3  = (const float*)d_in[6];
    const float* b3  = (const float*)d_in[7];
    const float* W4  = (const float*)d_in[8];
    const float* b4  = (const float*)d_in[9];
    char*  ws  = (char*)d_ws;
    float* out = (float*)d_out;

    static bool attr_set = false;
    if (!attr_set) {
        hipFuncSetAttribute(reinterpret_cast<const void*>(cnf_main),
                            hipFuncAttributeMaxDynamicSharedMemorySize, SMEM_BYTES);
        attr_set = true;
    }

    prep_w<<<(2 * 16 * 64 + 255) / 256, 256, 0, stream>>>(W1, (short*)(ws + W1OFF), 64, 16, 2);
    prep_w<<<(8 * 16 * 64 + 255) / 256, 256, 0, stream>>>(W2, (short*)(ws + W2OFF), 256, 16, 8);
    prep_w<<<(8 * 16 * 64 + 255) / 256, 256, 0, stream>>>(W3, (short*)(ws + W3OFF), 256, 16, 8);
    prep_w<<<(8 * 4 * 64 + 255) / 256, 256, 0, stream>>>(W4, (short*)(ws + W4OFF), 256, 4, 8);
    prep_b<<<4, 256, 0, stream>>>(b1, b2, b3, b4, (float*)(ws + BOFF));

    cnf_main<<<BATCH / 64, 256, SMEM_BYTES, stream>>>(x, eps, ws, out);
}